// Round 22
// baseline (170.283 us; speedup 1.0000x reference)
//
#include <hip/hip_runtime.h>

#define NN 500
#define BB 32
#define TT 12
#define EMB 10

typedef short bf16x8 __attribute__((ext_vector_type(8)));
typedef float f32x16 __attribute__((ext_vector_type(16)));

__device__ __forceinline__ unsigned short f2bf(float x) {
    unsigned int u = __float_as_uint(x);
    u = (u + 0x7fffu + ((u >> 16) & 1u)) >> 16;   // round-to-nearest-even
    return (unsigned short)u;
}

// ---------------- K_pre: fused softmaxS (blocks 0..499) + smallpre (500..999) + wpackB (1000..1017)
__global__ __launch_bounds__(256) void k_pre(const float* __restrict__ E,
                                             const int* __restrict__ stay,
                                             const float* __restrict__ wp,
                                             const float* __restrict__ bp,
                                             const float* __restrict__ wwsp,
                                             const float* __restrict__ wwtp,
                                             const float* __restrict__ wm,
                                             const float* __restrict__ wx,
                                             float* __restrict__ S,
                                             float* __restrict__ W,
                                             float* __restrict__ biasN,
                                             float* __restrict__ wws,
                                             float* __restrict__ wwt,
                                             unsigned short* __restrict__ wq) {
    const int bid = blockIdx.x;
    const int tid = threadIdx.x;
    if (bid < NN) {
        // ---- softmax row bid ----
        __shared__ float row[NN];
        __shared__ float red[256];
        const int i = bid;
        float ei[EMB];
#pragma unroll
        for (int d = 0; d < EMB; ++d) ei[d] = E[i * EMB + d];
        const float stayf = (float)stay[0];

        float lmax = -1e30f;
        for (int j = tid; j < NN; j += 256) {
            float acc = 0.f;
#pragma unroll
            for (int d = 0; d < EMB; ++d) acc += ei[d] * E[j * EMB + d];
            float v = acc > 0.f ? acc : 0.f;
            if (j == i) v = stayf;
            row[j] = v;
            lmax = fmaxf(lmax, v);
        }
        red[tid] = lmax;
        __syncthreads();
        for (int s = 128; s > 0; s >>= 1) {
            if (tid < s) red[tid] = fmaxf(red[tid], red[tid + s]);
            __syncthreads();
        }
        const float rmax = red[0];
        __syncthreads();

        float lsum = 0.f;
        for (int j = tid; j < NN; j += 256) {
            float e = __expf(row[j] - rmax);
            row[j] = e;
            lsum += e;
        }
        red[tid] = lsum;
        __syncthreads();
        for (int s = 128; s > 0; s >>= 1) {
            if (tid < s) red[tid] += red[tid + s];
            __syncthreads();
        }
        const float inv = 1.0f / red[0];
        for (int j = tid; j < NN; j += 256) S[i * NN + j] = row[j] * inv;
    } else if (bid < 2 * NN) {
        // ---- smallpre node n ----
        const int n = bid - NN;
        __shared__ float e[EMB];
        if (tid < EMB) e[tid] = E[n * EMB + tid];
        __syncthreads();
        if (tid < 144) {
            float acc = 0.f;
#pragma unroll
            for (int d = 0; d < EMB; ++d) acc += e[d] * wp[d * 144 + tid];
            W[n * 144 + tid] = acc;
        } else if (tid < 208) {
            const int o = tid - 144;
            float acc = 0.f;
#pragma unroll
            for (int d = 0; d < EMB; ++d) acc += e[d] * bp[d * 64 + o];
            biasN[n * 64 + o] = acc;
        } else if (tid < 216) {
            const int o = tid - 208;
            float acc = 0.f;
#pragma unroll
            for (int d = 0; d < EMB; ++d) acc += e[d] * wwsp[d * 8 + o];
            wws[n * 8 + o] = acc;
        } else if (tid < 224) {
            const int o = tid - 216;
            float acc = 0.f;
#pragma unroll
            for (int d = 0; d < EMB; ++d) acc += e[d] * wwtp[d * 8 + o];
            wwt[n * 8 + o] = acc;
        }
    } else {
        // ---- wpackB ----
        const int i = (bid - 2 * NN) * 256 + tid;
        if (i < 9 * 64 * 8) {
            const int j = i & 7;
            const int rest = i >> 3;
            const int lane = rest & 63;
            const int s = rest >> 6;
            const int kh = s / 3, kw = s - kh * 3;
            const int n = lane & 31;
            const int t = (lane >> 5) * 8 + j;
            float v = 0.f;
            if (t < TT) {
                if (n < 4) v = wm[((n * TT + t) * 3 + kh) * 3 + kw];
                else if (n < 8) v = wx[(((n - 4) * TT + t) * 3 + kh) * 3 + kw];
            }
            wq[i] = f2bf(v);
        }
    }
}

// ---------------- K_mv1: fused y1 = S^T-matvec (x 0..124) + Mwsum (x 125..128) ----------------
__global__ __launch_bounds__(256) void k_mv1(const float* __restrict__ S,
                                             const float* __restrict__ x,
                                             const float* __restrict__ xwin,
                                             const int* __restrict__ bidx,
                                             const int* __restrict__ jumpc,
                                             const float* __restrict__ Tp,
                                             float* __restrict__ y1,
                                             float* __restrict__ M,
                                             float* __restrict__ wsum) {
    const int b = blockIdx.y;
    const int tid = threadIdx.x;
    if (blockIdx.x < 125) {
        const int w = tid >> 6;
        const int lane = tid & 63;
        const int n = blockIdx.x * 4 + w;
        const float* xb = x + b * NN;
        const float* Sr = S + n * NN;
        float acc = 0.f;
        for (int m = lane; m < NN; m += 64) acc += Sr[m] * xb[m];
#pragma unroll
        for (int off = 32; off > 0; off >>= 1) acc += __shfl_down(acc, off, 64);
        if (lane == 0) y1[b * NN + n] = acc;
    } else {
        const int n0 = (blockIdx.x - 125) * 125;
        __shared__ float xsf[NN];
        __shared__ float Tl[TT];
        const int t0 = bidx[0], t1 = bidx[1], t2 = bidx[2];
        if (tid < TT) Tl[tid] = Tp[tid];
        const float* xb = xwin + (size_t)b * TT * NN;
        for (int m = tid; m < NN; m += 256)
            xsf[m] = xb[t0 * NN + m] + xb[t1 * NN + m] + xb[t2 * NN + m];
        __syncthreads();
        if (tid < 125) {
            const int n = n0 + tid;
            float ws_ = 0.f;
#pragma unroll
            for (int t = 0; t < TT; ++t) ws_ += xb[t * NN + n] * Tl[t];
            const float jc = (float)jumpc[0];
            const float jterm = jc * (2.f * xb[t0 * NN + n] + xb[t1 * NN + n]);
            float acc = 0.f;
            for (int m = 0; m < NN; ++m) acc += xsf[m] * S[m * NN + n];
            M[b * NN + n] = (acc + jterm) * (1.f / 3.f);
            wsum[b * NN + n] = ws_;
        }
    }
}

// ---------------- K2/K3: y[b,n] = sum_m S[n,m] * xin[b,m] (wave per row) ----------------
__global__ __launch_bounds__(256) void k_matvecS(const float* __restrict__ S,
                                                 const float* __restrict__ xin,
                                                 float* __restrict__ yout) {
    const int b = blockIdx.y;
    const int w = threadIdx.x >> 6;
    const int lane = threadIdx.x & 63;
    const int n = blockIdx.x * 4 + w;
    const float* xb = xin + b * NN;
    const float* Sr = S + n * NN;
    float acc = 0.f;
    for (int m = lane; m < NN; m += 64) acc += Sr[m] * xb[m];
#pragma unroll
    for (int off = 32; off > 0; off >>= 1) acc += __shfl_down(acc, off, 64);
    if (lane == 0) yout[b * NN + n] = acc;
}

// ---------------- K6: fused dual conv via MFMA (R18 body) + element-wise running reduce ----
// Grid (32, BB): cb = x>>3 (col-block of 128), rb = x&7 (row band of 63; band 7 short).
// Row slot: [sc 0..131][24 bf16 t-slots] (48B/col, 16B-slot stride 3 -> conflict-free reads).
// Staging unit = (t-pair tp, col sc): 2 coalesced loads -> 1 v_cvt_pk_bf16_f32 -> 1 u32 write.
// Reduce: 16 independent running accumulators (no per-row horizontal chains).
#define SLOTW 132
#define SLOTS (SLOTW * 24)            // ushorts per row slot (3168)
#define SLOTW32 (SLOTW * 12)          // u32 words per row slot (1584)

__global__ __launch_bounds__(256, 2) void k_conv(const float* __restrict__ MPG,
                                                 const unsigned short* __restrict__ wq,
                                                 const float* __restrict__ bmv,
                                                 const float* __restrict__ bxv,
                                                 float* __restrict__ partials) {
    const int b = blockIdx.y;
    const int cb = blockIdx.x >> 3;
    const int rb = blockIdx.x & 7;
    const int C0 = cb * 128;
    const int R0 = rb * 63;
    const int R1 = (R0 + 62 < NN - 1) ? R0 + 62 : NN - 1;
    const int tid = threadIdx.x;
    const int w = __builtin_amdgcn_readfirstlane(tid >> 6);
    const int lane = tid & 63;
    const int hi = lane >> 5;

    __shared__ unsigned short lsd[4 * SLOTS];
    __shared__ float wred[4][8][2];

    const float* basef = MPG + (size_t)b * TT * NN * NN;
    unsigned int* L32 = reinterpret_cast<unsigned int*>(lsd);

    // ---- B fragments (weights) ----
    bf16x8 bfq[9];
#pragma unroll
    for (int s = 0; s < 9; ++s)
        bfq[s] = *reinterpret_cast<const bf16x8*>(wq + (s * 64 + lane) * 8);

    // ---- staging units: f = tid + k*256 over 792 units (6 t-pairs x 132 cols) ----
    bool uval[4], uco[4];
    size_t g0[4];
    int ud[4];
#pragma unroll
    for (int k = 0; k < 4; ++k) {
        const int f = tid + k * 256;
        uval[k] = (f < 6 * SLOTW);
        const int tp = uval[k] ? (f / SLOTW) : 0;
        const int sc = uval[k] ? (f - tp * SLOTW) : 0;
        const int gcol = C0 - 1 + sc;
        uco[k] = uval[k] && (gcol >= 0) && (gcol < NN);
        g0[k] = (size_t)(2 * tp) * (NN * NN) + (uco[k] ? gcol : 0);
        ud[k] = sc * 12 + tp;          // u32 word within slot; low ushort = t=2tp
    }

    // ---- zero the t=12..15 pad words (sc*12+6, +7) in all 4 slots ----
    for (int z = tid; z < 4 * SLOTW; z += 256) {
        const int s = z / SLOTW;
        const int sc = z - s * SLOTW;
        L32[s * SLOTW32 + sc * 12 + 6] = 0u;
        L32[s * SLOTW32 + sc * 12 + 7] = 0u;
    }

    // ---- per-lane constants ----
    const int ch = lane & 31;
    const float biasv = (ch < 4) ? bmv[ch] : ((ch < 8) ? bxv[ch - 4] : 0.f);
    const bool interior = (C0 + w * 32 + 31) < NN;   // wave-uniform
    float mkv[16];
#pragma unroll
    for (int i = 0; i < 16; ++i) {
        const int p = C0 + w * 32 + (i & 3) + 8 * (i >> 2) + 4 * hi;
        mkv[i] = (p < NN) ? 1.f : 0.f;
    }
    const int aoff = (w * 32 + ch) * 48 + hi * 16;   // bytes within slot

    auto STAGE_LOAD = [&](int rr, float (&v0)[4], float (&v1)[4]) {
        const bool rowok = (rr >= 0) && (rr < NN);
#pragma unroll
        for (int k = 0; k < 4; ++k) {
            v0[k] = 0.f; v1[k] = 0.f;
            if (uco[k] && rowok) {
                const size_t o = g0[k] + (size_t)rr * NN;
                v0[k] = basef[o];
                v1[k] = basef[o + (size_t)NN * NN];
            }
        }
    };
    auto STAGE_WRITE = [&](int rr, const float (&v0)[4], const float (&v1)[4]) {
        unsigned int* dst = L32 + ((rr + 1) & 3) * SLOTW32;
#pragma unroll
        for (int k = 0; k < 4; ++k) {
            if (uval[k]) {
                unsigned int r;
                asm("v_cvt_pk_bf16_f32 %0, %1, %2" : "=v"(r) : "v"(v0[k]), "v"(v1[k]));
                dst[ud[k]] = r;
            }
        }
    };

    // ---- prologue: stage rows R0-1, R0, R0+1 into slots (row+1)&3 ----
#pragma unroll
    for (int q = 0; q < 3; ++q) {
        float v0[4], v1[4];
        STAGE_LOAD(R0 - 1 + q, v0, v1);
        STAGE_WRITE(R0 - 1 + q, v0, v1);
    }
    __syncthreads();

    // element-wise running accumulators (16 independent chains)
    float s16[16], m16[16];
#pragma unroll
    for (int i = 0; i < 16; ++i) { s16[i] = 0.f; m16[i] = 0.f; }

#pragma unroll 1
    for (int r = R0; r <= R1; ++r) {
        // issue next-row staging loads early (T14)
        const int rr = r + 2;
        const bool do_stage = (rr <= R1 + 1);
        float v0[4], v1[4];
        if (do_stage) STAGE_LOAD(rr, v0, v1);

        // compute: 9 shifts accumulate into one 32x32 C tile
        f32x16 acc;
#pragma unroll
        for (int i = 0; i < 16; ++i) acc[i] = biasv;
#pragma unroll
        for (int kh = 0; kh < 3; ++kh) {
            const char* sb = reinterpret_cast<const char*>(lsd) + ((r + kh) & 3) * (SLOTS * 2);
#pragma unroll
            for (int kw = 0; kw < 3; ++kw) {
                const bf16x8 a = *reinterpret_cast<const bf16x8*>(sb + aoff + kw * 48);
                acc = __builtin_amdgcn_mfma_f32_32x32x16_bf16(a, bfq[kh * 3 + kw], acc, 0, 0, 0);
            }
        }

        // relu + element-wise running reduce (no horizontal chains in the hot loop)
        if (interior) {
#pragma unroll
            for (int i = 0; i < 16; ++i) {
                const float v = fmaxf(acc[i], 0.f);
                s16[i] += v;
                m16[i] = fmaxf(m16[i], v);
            }
        } else {
#pragma unroll
            for (int i = 0; i < 16; ++i) {
                const float v = fmaxf(acc[i], 0.f) * mkv[i];
                s16[i] += v;
                m16[i] = fmaxf(m16[i], v);
            }
        }

        // write staged row (slot (rr+1)&3; reads this step used slots (r..r+2)&3), 1 barrier/row
        if (do_stage) STAGE_WRITE(rr, v0, v1);
        __syncthreads();
    }

    // ---- one horizontal reduce per block ----
    float sumv = 0.f, maxv = 0.f;
#pragma unroll
    for (int i = 0; i < 16; ++i) {
        sumv += s16[i];
        maxv = fmaxf(maxv, m16[i]);
    }

    // ---- reduce: lane l and l^32 share channel ch ----
    sumv += __shfl_xor(sumv, 32, 64);
    maxv = fmaxf(maxv, __shfl_xor(maxv, 32, 64));
    if (lane < 8) {
        wred[w][lane][0] = sumv;
        wred[w][lane][1] = maxv;
    }
    __syncthreads();
    if (tid < 8) {
        const float s = wred[0][tid][0] + wred[1][tid][0] + wred[2][tid][0] + wred[3][tid][0];
        const float mx = fmaxf(fmaxf(wred[0][tid][1], wred[1][tid][1]),
                               fmaxf(wred[2][tid][1], wred[3][tid][1]));
        partials[((size_t)b * 32 + blockIdx.x) * 8 + tid] = (tid < 4) ? s : mx;
    }
}

// ---------------- K7: reduce partials[b][32][8] -> topo[b][8] ----------------
__global__ __launch_bounds__(256) void k_topo(const float* __restrict__ partials,
                                              float* __restrict__ topo) {
    const int b = blockIdx.x;
    const int tid = threadIdx.x;
    const int c = tid & 7;
    const int g = tid >> 3;  // 32 groups -> one partial each
    float vs = 0.f, vm = 0.f;
    if (g < 32) {
        const float v = partials[((size_t)b * 32 + g) * 8 + c];
        vs = v;
        vm = v;
    }
    __shared__ float red[256];
    red[tid] = (c < 4) ? vs : vm;
    __syncthreads();
    for (int s = 16; s > 0; s >>= 1) {
        if (g < s) {
            const float a = red[tid];
            const float bv = red[tid + s * 8];
            red[tid] = (c < 4) ? (a + bv) : fmaxf(a, bv);
        }
        __syncthreads();
    }
    if (tid < 8) topo[b * 8 + tid] = (tid < 4) ? red[tid] * (1.f / (NN * (float)NN)) : red[tid];
}

// ---------------- K8: assemble output ----------------
__global__ __launch_bounds__(64) void k_out(const float* __restrict__ x,
                                            const float* __restrict__ y1,
                                            const float* __restrict__ y2,
                                            const float* __restrict__ W,
                                            const float* __restrict__ biasN,
                                            const float* __restrict__ wws,
                                            const float* __restrict__ wwt,
                                            const float* __restrict__ M,
                                            const float* __restrict__ wsum,
                                            const float* __restrict__ topo,
                                            float* __restrict__ out) {
    const int bn = blockIdx.x;
    const int b = bn / NN;
    const int n = bn - b * NN;
    const int o = threadIdx.x;
    float val;
    if (o < 48) {
        val = x[bn] * W[n * 144 + o] + y1[bn] * W[n * 144 + 48 + o] + y2[bn] * W[n * 144 + 96 + o];
    } else if (o < 56) {
        const int oo = o - 48;
        val = M[bn] * wws[n * 8 + oo] * topo[b * 8 + oo];
    } else {
        const int oo = o - 56;
        val = wsum[bn] * wwt[n * 8 + oo];
    }
    out[(size_t)bn * 64 + o] = val + biasN[n * 64 + o];
}

extern "C" void kernel_launch(void* const* d_in, const int* in_sizes, int n_in,
                              void* d_out, int out_size, void* d_ws, size_t ws_size,
                              hipStream_t stream) {
    const float* x    = (const float*)d_in[0];
    const float* xw   = (const float*)d_in[1];
    const float* E    = (const float*)d_in[2];
    const float* MPG  = (const float*)d_in[4];
    const int*   bidx = (const int*)d_in[5];
    const int*   stay = (const int*)d_in[7];
    const int*   jump = (const int*)d_in[8];
    const float* wp   = (const float*)d_in[9];
    const float* wwsp = (const float*)d_in[10];
    const float* wwtp = (const float*)d_in[11];
    const float* bp   = (const float*)d_in[12];
    const float* Tp   = (const float*)d_in[13];
    const float* cmw  = (const float*)d_in[14];
    const float* cmb  = (const float*)d_in[15];
    const float* cxw  = (const float*)d_in[16];
    const float* cxb  = (const float*)d_in[17];
    float* out = (float*)d_out;

    float* w = (float*)d_ws;
    float* S     = w;               // 250000
    float* y1    = S + 250000;      // 16000
    float* y2    = y1 + 16000;      // 16000
    float* W     = y2 + 16000;      // 72000
    float* biasN = W + 72000;       // 32000
    float* wws   = biasN + 32000;   // 4000
    float* wwt   = wws + 4000;      // 4000
    float* M     = wwt + 4000;      // 16000
    float* wsum  = M + 16000;       // 16000
    float* parts = wsum + 16000;    // 8192 (32 b x 32 blk x 8)
    float* topo  = parts + 8192;    // 256
    float* wpckf = topo + 256;      // 2304 floats = 4608 ushorts B-fragments
    unsigned short* wq = (unsigned short*)wpckf;

    k_pre<<<2 * NN + 18, 256, 0, stream>>>(E, stay, wp, bp, wwsp, wwtp, cmw, cxw,
                                           S, W, biasN, wws, wwt, wq);
    k_mv1<<<dim3(129, BB), 256, 0, stream>>>(S, x, xw, bidx, jump, Tp, y1, M, wsum);
    k_matvecS<<<dim3(125, BB), 256, 0, stream>>>(S, y1, y2);
    k_conv<<<dim3(32, BB), 256, 0, stream>>>(MPG, wq, cmb, cxb, parts);
    k_topo<<<BB, 256, 0, stream>>>(parts, topo);
    k_out<<<BB * NN, 64, 0, stream>>>(x, y1, y2, W, biasN, wws, wwt, M, wsum, topo, out);
}

// Round 23
// 132.226 us; speedup vs baseline: 1.2878x; 1.2878x over previous
//
#include <hip/hip_runtime.h>

#define NN 500
#define BB 32
#define TT 12
#define EMB 10

typedef short bf16x8 __attribute__((ext_vector_type(8)));
typedef float f32x16 __attribute__((ext_vector_type(16)));

__device__ __forceinline__ unsigned short f2bf(float x) {
    unsigned int u = __float_as_uint(x);
    u = (u + 0x7fffu + ((u >> 16) & 1u)) >> 16;   // round-to-nearest-even
    return (unsigned short)u;
}

// ---------------- K_pre: fused softmaxS (blocks 0..499) + smallpre (500..999) + wpackB (1000..1017)
__global__ __launch_bounds__(256) void k_pre(const float* __restrict__ E,
                                             const int* __restrict__ stay,
                                             const float* __restrict__ wp,
                                             const float* __restrict__ bp,
                                             const float* __restrict__ wwsp,
                                             const float* __restrict__ wwtp,
                                             const float* __restrict__ wm,
                                             const float* __restrict__ wx,
                                             float* __restrict__ S,
                                             float* __restrict__ W,
                                             float* __restrict__ biasN,
                                             float* __restrict__ wws,
                                             float* __restrict__ wwt,
                                             unsigned short* __restrict__ wq) {
    const int bid = blockIdx.x;
    const int tid = threadIdx.x;
    if (bid < NN) {
        __shared__ float row[NN];
        __shared__ float red[256];
        const int i = bid;
        float ei[EMB];
#pragma unroll
        for (int d = 0; d < EMB; ++d) ei[d] = E[i * EMB + d];
        const float stayf = (float)stay[0];

        float lmax = -1e30f;
        for (int j = tid; j < NN; j += 256) {
            float acc = 0.f;
#pragma unroll
            for (int d = 0; d < EMB; ++d) acc += ei[d] * E[j * EMB + d];
            float v = acc > 0.f ? acc : 0.f;
            if (j == i) v = stayf;
            row[j] = v;
            lmax = fmaxf(lmax, v);
        }
        red[tid] = lmax;
        __syncthreads();
        for (int s = 128; s > 0; s >>= 1) {
            if (tid < s) red[tid] = fmaxf(red[tid], red[tid + s]);
            __syncthreads();
        }
        const float rmax = red[0];
        __syncthreads();

        float lsum = 0.f;
        for (int j = tid; j < NN; j += 256) {
            float e = __expf(row[j] - rmax);
            row[j] = e;
            lsum += e;
        }
        red[tid] = lsum;
        __syncthreads();
        for (int s = 128; s > 0; s >>= 1) {
            if (tid < s) red[tid] += red[tid + s];
            __syncthreads();
        }
        const float inv = 1.0f / red[0];
        for (int j = tid; j < NN; j += 256) S[i * NN + j] = row[j] * inv;
    } else if (bid < 2 * NN) {
        const int n = bid - NN;
        __shared__ float e[EMB];
        if (tid < EMB) e[tid] = E[n * EMB + tid];
        __syncthreads();
        if (tid < 144) {
            float acc = 0.f;
#pragma unroll
            for (int d = 0; d < EMB; ++d) acc += e[d] * wp[d * 144 + tid];
            W[n * 144 + tid] = acc;
        } else if (tid < 208) {
            const int o = tid - 144;
            float acc = 0.f;
#pragma unroll
            for (int d = 0; d < EMB; ++d) acc += e[d] * bp[d * 64 + o];
            biasN[n * 64 + o] = acc;
        } else if (tid < 216) {
            const int o = tid - 208;
            float acc = 0.f;
#pragma unroll
            for (int d = 0; d < EMB; ++d) acc += e[d] * wwsp[d * 8 + o];
            wws[n * 8 + o] = acc;
        } else if (tid < 224) {
            const int o = tid - 216;
            float acc = 0.f;
#pragma unroll
            for (int d = 0; d < EMB; ++d) acc += e[d] * wwtp[d * 8 + o];
            wwt[n * 8 + o] = acc;
        }
    } else {
        const int i = (bid - 2 * NN) * 256 + tid;
        if (i < 9 * 64 * 8) {
            const int j = i & 7;
            const int rest = i >> 3;
            const int lane = rest & 63;
            const int s = rest >> 6;
            const int kh = s / 3, kw = s - kh * 3;
            const int n = lane & 31;
            const int t = (lane >> 5) * 8 + j;
            float v = 0.f;
            if (t < TT) {
                if (n < 4) v = wm[((n * TT + t) * 3 + kh) * 3 + kw];
                else if (n < 8) v = wx[(((n - 4) * TT + t) * 3 + kh) * 3 + kw];
            }
            wq[i] = f2bf(v);
        }
    }
}

// ---------------- K_mv1: fused y1 = S^T-matvec (x 0..124) + Mwsum (x 125..128) ----------------
__global__ __launch_bounds__(256) void k_mv1(const float* __restrict__ S,
                                             const float* __restrict__ x,
                                             const float* __restrict__ xwin,
                                             const int* __restrict__ bidx,
                                             const int* __restrict__ jumpc,
                                             const float* __restrict__ Tp,
                                             float* __restrict__ y1,
                                             float* __restrict__ M,
                                             float* __restrict__ wsum) {
    const int b = blockIdx.y;
    const int tid = threadIdx.x;
    if (blockIdx.x < 125) {
        const int w = tid >> 6;
        const int lane = tid & 63;
        const int n = blockIdx.x * 4 + w;
        const float* xb = x + b * NN;
        const float* Sr = S + n * NN;
        float acc = 0.f;
        for (int m = lane; m < NN; m += 64) acc += Sr[m] * xb[m];
#pragma unroll
        for (int off = 32; off > 0; off >>= 1) acc += __shfl_down(acc, off, 64);
        if (lane == 0) y1[b * NN + n] = acc;
    } else {
        const int n0 = (blockIdx.x - 125) * 125;
        __shared__ float xsf[NN];
        __shared__ float Tl[TT];
        const int t0 = bidx[0], t1 = bidx[1], t2 = bidx[2];
        if (tid < TT) Tl[tid] = Tp[tid];
        const float* xb = xwin + (size_t)b * TT * NN;
        for (int m = tid; m < NN; m += 256)
            xsf[m] = xb[t0 * NN + m] + xb[t1 * NN + m] + xb[t2 * NN + m];
        __syncthreads();
        if (tid < 125) {
            const int n = n0 + tid;
            float ws_ = 0.f;
#pragma unroll
            for (int t = 0; t < TT; ++t) ws_ += xb[t * NN + n] * Tl[t];
            const float jc = (float)jumpc[0];
            const float jterm = jc * (2.f * xb[t0 * NN + n] + xb[t1 * NN + n]);
            float acc = 0.f;
            for (int m = 0; m < NN; ++m) acc += xsf[m] * S[m * NN + n];
            M[b * NN + n] = (acc + jterm) * (1.f / 3.f);
            wsum[b * NN + n] = ws_;
        }
    }
}

// ---------------- K2/K3: y[b,n] = sum_m S[n,m] * xin[b,m] (wave per row) ----------------
__global__ __launch_bounds__(256) void k_matvecS(const float* __restrict__ S,
                                                 const float* __restrict__ xin,
                                                 float* __restrict__ yout) {
    const int b = blockIdx.y;
    const int w = threadIdx.x >> 6;
    const int lane = threadIdx.x & 63;
    const int n = blockIdx.x * 4 + w;
    const float* xb = xin + b * NN;
    const float* Sr = S + n * NN;
    float acc = 0.f;
    for (int m = lane; m < NN; m += 64) acc += Sr[m] * xb[m];
#pragma unroll
    for (int off = 32; off > 0; off >>= 1) acc += __shfl_down(acc, off, 64);
    if (lane == 0) yout[b * NN + n] = acc;
}

// ---------------- K6: fused dual conv via MFMA (R18 body, byte-exact) ----------
// Grid (32, BB): cb = x>>3 (col-block of 128), rb = x&7 (row band of 63; band 7 short).
// Row slot: [sc 0..131][24 bf16 t-slots] (48B/col, 16B-slot stride 3 -> conflict-free reads).
// Staging unit = (t-pair tp, col sc): 2 coalesced loads -> 1 v_cvt_pk_bf16_f32 -> 1 u32 write.
#define SLOTW 132
#define SLOTS (SLOTW * 24)            // ushorts per row slot (3168)
#define SLOTW32 (SLOTW * 12)          // u32 words per row slot (1584)

__global__ __launch_bounds__(256, 2) void k_conv(const float* __restrict__ MPG,
                                                 const unsigned short* __restrict__ wq,
                                                 const float* __restrict__ bmv,
                                                 const float* __restrict__ bxv,
                                                 float* __restrict__ partials) {
    const int b = blockIdx.y;
    const int cb = blockIdx.x >> 3;
    const int rb = blockIdx.x & 7;
    const int C0 = cb * 128;
    const int R0 = rb * 63;
    const int R1 = (R0 + 62 < NN - 1) ? R0 + 62 : NN - 1;
    const int tid = threadIdx.x;
    const int w = __builtin_amdgcn_readfirstlane(tid >> 6);
    const int lane = tid & 63;
    const int hi = lane >> 5;

    __shared__ unsigned short lsd[4 * SLOTS];
    __shared__ float wred[4][8][2];

    const float* basef = MPG + (size_t)b * TT * NN * NN;
    unsigned int* L32 = reinterpret_cast<unsigned int*>(lsd);

    bf16x8 bfq[9];
#pragma unroll
    for (int s = 0; s < 9; ++s)
        bfq[s] = *reinterpret_cast<const bf16x8*>(wq + (s * 64 + lane) * 8);

    bool uval[4], uco[4];
    size_t g0[4];
    int ud[4];
#pragma unroll
    for (int k = 0; k < 4; ++k) {
        const int f = tid + k * 256;
        uval[k] = (f < 6 * SLOTW);
        const int tp = uval[k] ? (f / SLOTW) : 0;
        const int sc = uval[k] ? (f - tp * SLOTW) : 0;
        const int gcol = C0 - 1 + sc;
        uco[k] = uval[k] && (gcol >= 0) && (gcol < NN);
        g0[k] = (size_t)(2 * tp) * (NN * NN) + (uco[k] ? gcol : 0);
        ud[k] = sc * 12 + tp;          // u32 word within slot; low ushort = t=2tp
    }

    for (int z = tid; z < 4 * SLOTW; z += 256) {
        const int s = z / SLOTW;
        const int sc = z - s * SLOTW;
        L32[s * SLOTW32 + sc * 12 + 6] = 0u;
        L32[s * SLOTW32 + sc * 12 + 7] = 0u;
    }

    const int ch = lane & 31;
    const float biasv = (ch < 4) ? bmv[ch] : ((ch < 8) ? bxv[ch - 4] : 0.f);
    const bool interior = (C0 + w * 32 + 31) < NN;   // wave-uniform
    float mkv[16];
#pragma unroll
    for (int i = 0; i < 16; ++i) {
        const int p = C0 + w * 32 + (i & 3) + 8 * (i >> 2) + 4 * hi;
        mkv[i] = (p < NN) ? 1.f : 0.f;
    }
    const int aoff = (w * 32 + ch) * 48 + hi * 16;   // bytes within slot

    auto STAGE_LOAD = [&](int rr, float (&v0)[4], float (&v1)[4]) {
        const bool rowok = (rr >= 0) && (rr < NN);
#pragma unroll
        for (int k = 0; k < 4; ++k) {
            v0[k] = 0.f; v1[k] = 0.f;
            if (uco[k] && rowok) {
                const size_t o = g0[k] + (size_t)rr * NN;
                v0[k] = basef[o];
                v1[k] = basef[o + (size_t)NN * NN];
            }
        }
    };
    auto STAGE_WRITE = [&](int rr, const float (&v0)[4], const float (&v1)[4]) {
        unsigned int* dst = L32 + ((rr + 1) & 3) * SLOTW32;
#pragma unroll
        for (int k = 0; k < 4; ++k) {
            if (uval[k]) {
                unsigned int r;
                asm("v_cvt_pk_bf16_f32 %0, %1, %2" : "=v"(r) : "v"(v0[k]), "v"(v1[k]));
                dst[ud[k]] = r;
            }
        }
    };

#pragma unroll
    for (int q = 0; q < 3; ++q) {
        float v0[4], v1[4];
        STAGE_LOAD(R0 - 1 + q, v0, v1);
        STAGE_WRITE(R0 - 1 + q, v0, v1);
    }
    __syncthreads();

    float sumv = 0.f, maxv = 0.f;

#pragma unroll 1
    for (int r = R0; r <= R1; ++r) {
        const int rr = r + 2;
        const bool do_stage = (rr <= R1 + 1);
        float v0[4], v1[4];
        if (do_stage) STAGE_LOAD(rr, v0, v1);

        f32x16 acc;
#pragma unroll
        for (int i = 0; i < 16; ++i) acc[i] = biasv;
#pragma unroll
        for (int kh = 0; kh < 3; ++kh) {
            const char* sb = reinterpret_cast<const char*>(lsd) + ((r + kh) & 3) * (SLOTS * 2);
#pragma unroll
            for (int kw = 0; kw < 3; ++kw) {
                const bf16x8 a = *reinterpret_cast<const bf16x8*>(sb + aoff + kw * 48);
                acc = __builtin_amdgcn_mfma_f32_32x32x16_bf16(a, bfq[kh * 3 + kw], acc, 0, 0, 0);
            }
        }

        if (interior) {
            float rs = 0.f;
#pragma unroll
            for (int i = 0; i < 16; ++i) rs += fmaxf(acc[i], 0.f);
            sumv += rs;
            float mm = acc[0];
#pragma unroll
            for (int i = 1; i < 16; ++i) mm = fmaxf(mm, acc[i]);
            maxv = fmaxf(maxv, mm);
        } else {
#pragma unroll
            for (int i = 0; i < 16; ++i) {
                const float v = fmaxf(acc[i], 0.f) * mkv[i];
                sumv += v;
                maxv = fmaxf(maxv, v);
            }
        }

        if (do_stage) STAGE_WRITE(rr, v0, v1);
        __syncthreads();
    }

    sumv += __shfl_xor(sumv, 32, 64);
    maxv = fmaxf(maxv, __shfl_xor(maxv, 32, 64));
    if (lane < 8) {
        wred[w][lane][0] = sumv;
        wred[w][lane][1] = maxv;
    }
    __syncthreads();
    if (tid < 8) {
        const float s = wred[0][tid][0] + wred[1][tid][0] + wred[2][tid][0] + wred[3][tid][0];
        const float mx = fmaxf(fmaxf(wred[0][tid][1], wred[1][tid][1]),
                               fmaxf(wred[2][tid][1], wred[3][tid][1]));
        partials[((size_t)b * 32 + blockIdx.x) * 8 + tid] = (tid < 4) ? s : mx;
    }
}

// ---------------- K7: reduce partials[b][32][8] -> topo[b][8] ----------------
__global__ __launch_bounds__(256) void k_topo(const float* __restrict__ partials,
                                              float* __restrict__ topo) {
    const int b = blockIdx.x;
    const int tid = threadIdx.x;
    const int c = tid & 7;
    const int g = tid >> 3;  // 32 groups -> one partial each
    float vs = 0.f, vm = 0.f;
    if (g < 32) {
        const float v = partials[((size_t)b * 32 + g) * 8 + c];
        vs = v;
        vm = v;
    }
    __shared__ float red[256];
    red[tid] = (c < 4) ? vs : vm;
    __syncthreads();
    for (int s = 16; s > 0; s >>= 1) {
        if (g < s) {
            const float a = red[tid];
            const float bv = red[tid + s * 8];
            red[tid] = (c < 4) ? (a + bv) : fmaxf(a, bv);
        }
        __syncthreads();
    }
    if (tid < 8) topo[b * 8 + tid] = (tid < 4) ? red[tid] * (1.f / (NN * (float)NN)) : red[tid];
}

// ---------------- K8: assemble output ----------------
__global__ __launch_bounds__(64) void k_out(const float* __restrict__ x,
                                            const float* __restrict__ y1,
                                            const float* __restrict__ y2,
                                            const float* __restrict__ W,
                                            const float* __restrict__ biasN,
                                            const float* __restrict__ wws,
                                            const float* __restrict__ wwt,
                                            const float* __restrict__ M,
                                            const float* __restrict__ wsum,
                                            const float* __restrict__ topo,
                                            float* __restrict__ out) {
    const int bn = blockIdx.x;
    const int b = bn / NN;
    const int n = bn - b * NN;
    const int o = threadIdx.x;
    float val;
    if (o < 48) {
        val = x[bn] * W[n * 144 + o] + y1[bn] * W[n * 144 + 48 + o] + y2[bn] * W[n * 144 + 96 + o];
    } else if (o < 56) {
        const int oo = o - 48;
        val = M[bn] * wws[n * 8 + oo] * topo[b * 8 + oo];
    } else {
        const int oo = o - 56;
        val = wsum[bn] * wwt[n * 8 + oo];
    }
    out[(size_t)bn * 64 + o] = val + biasN[n * 64 + o];
}

extern "C" void kernel_launch(void* const* d_in, const int* in_sizes, int n_in,
                              void* d_out, int out_size, void* d_ws, size_t ws_size,
                              hipStream_t stream) {
    const float* x    = (const float*)d_in[0];
    const float* xw   = (const float*)d_in[1];
    const float* E    = (const float*)d_in[2];
    const float* MPG  = (const float*)d_in[4];
    const int*   bidx = (const int*)d_in[5];
    const int*   stay = (const int*)d_in[7];
    const int*   jump = (const int*)d_in[8];
    const float* wp   = (const float*)d_in[9];
    const float* wwsp = (const float*)d_in[10];
    const float* wwtp = (const float*)d_in[11];
    const float* bp   = (const float*)d_in[12];
    const float* Tp   = (const float*)d_in[13];
    const float* cmw  = (const float*)d_in[14];
    const float* cmb  = (const float*)d_in[15];
    const float* cxw  = (const float*)d_in[16];
    const float* cxb  = (const float*)d_in[17];
    float* out = (float*)d_out;

    float* w = (float*)d_ws;
    float* S     = w;               // 250000
    float* y1    = S + 250000;      // 16000
    float* y2    = y1 + 16000;      // 16000
    float* W     = y2 + 16000;      // 72000
    float* biasN = W + 72000;       // 32000
    float* wws   = biasN + 32000;   // 4000
    float* wwt   = wws + 4000;      // 4000
    float* M     = wwt + 4000;      // 16000
    float* wsum  = M + 16000;       // 16000
    float* parts = wsum + 16000;    // 8192 (32 b x 32 blk x 8)
    float* topo  = parts + 8192;    // 256
    float* wpckf = topo + 256;      // 2304 floats = 4608 ushorts B-fragments
    unsigned short* wq = (unsigned short*)wpckf;

    k_pre<<<2 * NN + 18, 256, 0, stream>>>(E, stay, wp, bp, wwsp, wwtp, cmw, cxw,
                                           S, W, biasN, wws, wwt, wq);
    k_mv1<<<dim3(129, BB), 256, 0, stream>>>(S, x, xw, bidx, jump, Tp, y1, M, wsum);
    k_matvecS<<<dim3(125, BB), 256, 0, stream>>>(S, y1, y2);
    k_conv<<<dim3(32, BB), 256, 0, stream>>>(MPG, wq, cmb, cxb, parts);
    k_topo<<<BB, 256, 0, stream>>>(parts, topo);
    k_out<<<BB * NN, 64, 0, stream>>>(x, y1, y2, W, biasN, wws, wwt, M, wsum, topo, out);
}